// Round 12
// baseline (249.327 us; speedup 1.0000x reference)
//
#include <hip/hip_runtime.h>
#include <hip/hip_bf16.h>
#include <math.h>

// Problem constants: B=2, S=2048, H=768, NH=12, D=64, R=256, MAX_REL=128
// BH = 24; QKV GEMM rows M = 4096.

#define LDS_ATOMIC_ADD(p, v) __hip_atomic_fetch_add((p), (v), __ATOMIC_RELAXED, __HIP_MEMORY_SCOPE_WORKGROUP)

typedef short short8v __attribute__((ext_vector_type(8)));
typedef short short4v __attribute__((ext_vector_type(4)));
typedef float f32x4 __attribute__((ext_vector_type(4)));

#define MFMA16x16x32(a, b, c) __builtin_amdgcn_mfma_f32_16x16x32_bf16((a), (b), (c), 0, 0, 0)

// float -> bf16 bits, round-to-nearest-even (values are finite here)
__device__ inline short f2bf(float f) {
  unsigned u = __float_as_uint(f);
  unsigned r = (u + 0x7FFFu + ((u >> 16) & 1u)) >> 16;
  return (short)r;
}
__device__ inline float bf2f(short b) {
  return __uint_as_float(((unsigned)(unsigned short)b) << 16);
}

// ---------------- Prep B: W [768k][768n] -> WT bf16 [w][768n][768k] ----------------
__global__ __launch_bounds__(256) void prep_wt_kernel(
    const float* __restrict__ Wq, const float* __restrict__ Wk,
    const float* __restrict__ Wv, short* __restrict__ wt) {
  __shared__ float tile[64][65];
  const int t = threadIdx.x, tx = t & 15, ty = t >> 4;
  const int w = blockIdx.z;
  const float* W = (w == 0) ? Wq : (w == 1) ? Wk : Wv;
  const int k0 = blockIdx.x * 64, n0 = blockIdx.y * 64;
  #pragma unroll
  for (int rr = 0; rr < 4; ++rr) {
    const int kr = rr * 16 + ty;
    const float4 v = *(const float4*)&W[(size_t)(k0 + kr) * 768 + n0 + tx * 4];
    tile[kr][tx*4 + 0] = v.x; tile[kr][tx*4 + 1] = v.y;
    tile[kr][tx*4 + 2] = v.z; tile[kr][tx*4 + 3] = v.w;
  }
  __syncthreads();
  #pragma unroll
  for (int rr = 0; rr < 4; ++rr) {
    const int nr = rr * 16 + ty;
    short4v s;
    #pragma unroll
    for (int c = 0; c < 4; ++c) s[c] = f2bf(tile[tx*4 + c][nr]);
    *(short4v*)&wt[((size_t)w * 768 + n0 + nr) * 768 + k0 + tx * 4] = s;
  }
}

// ---------------- Prep C: rvet = rve^T bf16 [64][256]; rkeb = rke bf16 ----------------
__global__ __launch_bounds__(256) void rvet_kernel(
    const float* __restrict__ rve, const float* __restrict__ rke,
    short* __restrict__ rvet, short* __restrict__ rkeb) {
  const int idx = blockIdx.x * 256 + threadIdx.x;   // 0..16383
  const int r = idx >> 6, d = idx & 63;
  rvet[d*256 + r] = f2bf(rve[idx]);
  rkeb[idx]       = f2bf(rke[idx]);
}

// ---------------- Kernel 1: QKV projection, MFMA bf16 (single-A) ----------------
// hs read as f32, converted to bf16 in-register at staging time.
// Outputs in [bh][s][64] layout; V transposed by transpose_v_kernel.
__global__ __launch_bounds__(256) void qkv_mfma_kernel(
    const float* __restrict__ hs, const short* __restrict__ wt,
    const float* __restrict__ bq, const float* __restrict__ bk,
    const float* __restrict__ bv,
    short* __restrict__ qbf, short* __restrict__ kbf, short* __restrict__ vbf) {
  __shared__ short lds[2 * 8192];
  short* Ah = lds;                 // [128][64] swizzled
  short* Bt = lds + 8192;          // [128 n-rows][64 k]

  const int t = threadIdx.x, lane = t & 63, wv = t >> 6;
  const int wm = wv & 1, wn = wv >> 1;
  const int lrow = lane & 15, g = lane >> 4;
  const int m0 = blockIdx.x * 128, n0 = blockIdx.y * 128, w = blockIdx.z;
  const short* Bg = wt + (size_t)w * 768 * 768;
  const float* bias = (w == 0) ? bq : (w == 1) ? bk : bv;
  short* outp = (w == 0) ? qbf : (w == 1) ? kbf : vbf;

  int srow[4], sc[4];
  #pragma unroll
  for (int e = 0; e < 4; ++e) {
    const int id = t + 256*e;
    srow[e] = id >> 3; sc[e] = id & 7;
  }

  // prologue: stage K-step 0
  #pragma unroll
  for (int e = 0; e < 4; ++e) {
    const int row = srow[e], c = sc[e];
    const int dst = row*64 + ((c ^ (row & 7)) * 8);
    const float* s = &hs[(size_t)(m0 + row)*768 + c*8];
    const float4 f0 = *(const float4*)s, f1 = *(const float4*)(s + 4);
    short8v hiv;
    hiv[0] = f2bf(f0.x); hiv[1] = f2bf(f0.y); hiv[2] = f2bf(f0.z); hiv[3] = f2bf(f0.w);
    hiv[4] = f2bf(f1.x); hiv[5] = f2bf(f1.y); hiv[6] = f2bf(f1.z); hiv[7] = f2bf(f1.w);
    *(short8v*)&Ah[dst] = hiv;
    *(short8v*)&Bt[dst] = *(const short8v*)&Bg[(size_t)(n0 + row)*768 + c*8];
  }
  __syncthreads();

  f32x4 acc[4][4] = {};

  for (int kt = 0; kt < 12; ++kt) {
    float4 pf0[4], pf1[4];
    short8v pb[4];
    const bool have_next = (kt < 11);
    if (have_next) {
      const int k0n = (kt + 1) * 64;
      #pragma unroll
      for (int e = 0; e < 4; ++e) {
        const int row = srow[e], c = sc[e];
        const float* s = &hs[(size_t)(m0 + row)*768 + k0n + c*8];
        pf0[e] = *(const float4*)s;
        pf1[e] = *(const float4*)(s + 4);
        pb[e]  = *(const short8v*)&Bg[(size_t)(n0 + row)*768 + k0n + c*8];
      }
    }

    #pragma unroll
    for (int kc = 0; kc < 2; ++kc) {
      short8v af[4], bfv[4];
      #pragma unroll
      for (int fm = 0; fm < 4; ++fm) {
        const int row = wm*64 + fm*16 + lrow;
        af[fm] = *(const short8v*)&Ah[row*64 + (((kc*4 + g) ^ (row & 7)) * 8)];
      }
      #pragma unroll
      for (int fn = 0; fn < 4; ++fn) {
        const int row = wn*64 + fn*16 + lrow;
        bfv[fn] = *(const short8v*)&Bt[row*64 + (((kc*4 + g) ^ (row & 7)) * 8)];
      }
      #pragma unroll
      for (int fm = 0; fm < 4; ++fm)
        #pragma unroll
        for (int fn = 0; fn < 4; ++fn)
          acc[fm][fn] = MFMA16x16x32(af[fm], bfv[fn], acc[fm][fn]);
    }
    __syncthreads();
    if (have_next) {
      #pragma unroll
      for (int e = 0; e < 4; ++e) {
        const int row = srow[e], c = sc[e];
        const int dst = row*64 + ((c ^ (row & 7)) * 8);
        short8v hiv;
        hiv[0] = f2bf(pf0[e].x); hiv[1] = f2bf(pf0[e].y);
        hiv[2] = f2bf(pf0[e].z); hiv[3] = f2bf(pf0[e].w);
        hiv[4] = f2bf(pf1[e].x); hiv[5] = f2bf(pf1[e].y);
        hiv[6] = f2bf(pf1[e].z); hiv[7] = f2bf(pf1[e].w);
        *(short8v*)&Ah[dst] = hiv;
        *(short8v*)&Bt[dst] = pb[e];
      }
    }
    __syncthreads();
  }

  float bias_v[4];
  #pragma unroll
  for (int fn = 0; fn < 4; ++fn) bias_v[fn] = bias[n0 + wn*64 + fn*16 + lrow];

  #pragma unroll
  for (int fm = 0; fm < 4; ++fm) {
    #pragma unroll
    for (int r = 0; r < 4; ++r) {
      const int m = m0 + wm*64 + fm*16 + g*4 + r;
      const int b = m >> 11, s = m & 2047;
      #pragma unroll
      for (int fn = 0; fn < 4; ++fn) {
        const int n = n0 + wn*64 + fn*16 + lrow;
        const int h = n >> 6, d = n & 63;
        const size_t bh = (size_t)b*12 + h;
        outp[(bh*2048 + s)*64 + d] = f2bf(acc[fm][fn][r] + bias_v[fn]);
      }
    }
  }
}

// ---------------- Kernel 1b: V transpose [bh][s][64] -> [bh][d][2048] ----------------
__global__ __launch_bounds__(256) void transpose_v_kernel(
    const short* __restrict__ vbf, short* __restrict__ vtbf) {
  __shared__ short tile[64][66];
  const int t = threadIdx.x;
  const int bh = blockIdx.y;
  const int s0 = blockIdx.x * 64;
  const short* src = vbf + ((size_t)bh*2048 + s0)*64;
  const int row = t >> 3, c = t & 7;   // row 0..31, c 0..7
  #pragma unroll
  for (int e = 0; e < 2; ++e) {
    const int r = row + 32*e;
    *(short8v*)&tile[r][c*8] = *(const short8v*)&src[(size_t)r*64 + c*8];
  }
  __syncthreads();
  #pragma unroll
  for (int e = 0; e < 2; ++e) {
    const int d = row + 32*e;
    short8v v;
    #pragma unroll
    for (int k = 0; k < 8; ++k) v[k] = tile[c*8 + k][d];
    *(short8v*)&vtbf[((size_t)bh*64 + d)*2048 + s0 + c*8] = v;
  }
}

// ---------------- Kernel 3: fused attention + rel_scores, MFMA bf16 ----------------
// rs and rp MERGED into one LDS array (rr): prologue writes rel_scores into
// every slot; the band phase reads slot (rel score) then overwrites it with
// the prob (each interior (il,bk) has exactly one (i,j) -> single visit).
// Stale rs survives only where j=gi+bk-128 is out of range -> zeroed by a
// predicated cleanup in the 8/64 edge i-blocks. LDS 37248 -> 4 blocks/CU.
__global__ __launch_bounds__(256) void attn_mfma_kernel(
    const short* __restrict__ qbf, const short* __restrict__ kbf,
    const short* __restrict__ vtbf, const short* __restrict__ rkeb,
    const short* __restrict__ rvet, const float* __restrict__ mask,
    float* __restrict__ out) {
  __shared__ __align__(16) char smem[37248];
  short* rr_bf   = (short*)smem;                 // [32*256] bf16 swizzled: rs then rp
  short* k_lds   = (short*)(smem + 16384);       // [64*64]                 8192 B
  short* vt_lds  = (short*)(smem + 24576);       // [64*64]                 8192 B
  short* qp_lds  = (short*)(smem + 32768);       // [32*64] q, then p       4096 B
  float* l_s     = (float*)(smem + 36864);       // [32]                     128 B
  float* edge_f  = (float*)(smem + 36992);       // [32][2]                  256 B

  const int t    = threadIdx.x;
  const int lane = t & 63, wv = t >> 6;
  const int ih   = wv & 1, jh = wv >> 1;
  const int lrow = lane & 15, g = lane >> 4;
  const int swz  = (lrow & 7) << 3;

  const int bh = blockIdx.y, b = bh / 12, h = bh % 12;
  const int i0 = blockIdx.x * 32;

  const short* qb  = qbf  + ((size_t)bh*2048 + i0)*64;
  const short* kb  = kbf  + (size_t)bh*2048*64;
  const short* vtb = vtbf + (size_t)bh*64*2048;
  const float* mb  = mask + (size_t)b*2048;

  if (t < 32) { l_s[t] = 0.f; edge_f[2*t] = 0.f; edge_f[2*t+1] = 0.f; }
  // stage q (32 rows x 8 chunks)
  {
    const int row = t >> 3, c = t & 7;
    *(short8v*)&qp_lds[row*64 + ((c ^ (row & 7))*8)] =
        *(const short8v*)&qb[row*64 + c*8];
  }
  // stage k/vt tile 0 (single buffers)
  #pragma unroll
  for (int e = 0; e < 2; ++e) {
    const int id = t + 256*e, row = id >> 3, c = id & 7;
    *(short8v*)&k_lds[row*64 + ((c ^ (row & 7))*8)] =
        *(const short8v*)&kb[(size_t)row*64 + c*8];
    *(short8v*)&vt_lds[row*64 + ((c ^ (row & 7))*8)] =
        *(const short8v*)&vtb[(size_t)row*2048 + c*8];
  }
  __syncthreads();                       // P1: staging visible

  // hoisted Q A-fragments (loop-invariant)
  const short8v aq0 = *(const short8v*)&qp_lds[(ih*16 + lrow)*64 + ((g*8) ^ swz)];
  const short8v aq1 = *(const short8v*)&qp_lds[(ih*16 + lrow)*64 + ((32 + g*8) ^ swz)];

  // --- fused rel_scores into rr_bf (all 32x256 slots) ---
  {
    f32x4 racc[2][4] = {};
    #pragma unroll
    for (int kc = 0; kc < 2; ++kc) {
      short8v am0 = *(const short8v*)&qp_lds[lrow*64 + (((kc*4 + g) ^ (lrow & 7))*8)];
      short8v am1 = *(const short8v*)&qp_lds[(16 + lrow)*64 + (((kc*4 + g) ^ ((16 + lrow) & 7))*8)];
      #pragma unroll
      for (int fn = 0; fn < 4; ++fn) {
        const short8v bb = *(const short8v*)&rkeb[(size_t)(wv*64 + fn*16 + lrow)*64 + kc*32 + g*8];
        racc[0][fn] = MFMA16x16x32(am0, bb, racc[0][fn]);
        racc[1][fn] = MFMA16x16x32(am1, bb, racc[1][fn]);
      }
    }
    #pragma unroll
    for (int mt = 0; mt < 2; ++mt)
      #pragma unroll
      for (int fn = 0; fn < 4; ++fn)
        #pragma unroll
        for (int r = 0; r < 4; ++r) {
          const int il = mt*16 + 4*g + r;
          const int bk = wv*64 + fn*16 + lrow;
          rr_bf[il*256 + (((bk >> 3) ^ (il & 7)) << 3) + (bk & 7)] =
              f2bf(racc[mt][fn][r] * 0.125f);
        }
  }
  __syncthreads();                       // P2: q reads + rs writes done

  float rs_lo[4], rs_hi[4];
  #pragma unroll
  for (int r = 0; r < 4; ++r) {
    const int il = ih*16 + 4*g + r;
    rs_lo[r] = bf2f(rr_bf[il*256 + ((il & 7) << 3)]);              // bucket 0
    rs_hi[r] = bf2f(rr_bf[il*256 + (((31 ^ (il & 7)) << 3) + 7)]); // bucket 255
  }
  float ls_p[4]  = {0,0,0,0};
  float rpl_p[4] = {0,0,0,0};
  float rph_p[4] = {0,0,0,0};
  f32x4 ctx0 = {0,0,0,0}, ctx1 = {0,0,0,0};

  const int srow0 = t >> 3, sc = t & 7, srow1 = (t >> 3) + 32;
  short8v stk0, stk1, stv0, stv1;

  for (int jt = 0; jt < 32; ++jt) {
    const int j0 = jt * 64;
    const bool have_next = (jt < 31);

    // v(jt) from regs -> LDS (post-B2(jt-1); all PV reads of v(jt-1) done)
    if (jt > 0) {
      *(short8v*)&vt_lds[srow0*64 + ((sc ^ (srow0 & 7))*8)] = stv0;
      *(short8v*)&vt_lds[srow1*64 + ((sc ^ (srow1 & 7))*8)] = stv1;
    }
    if (have_next) {                 // issue next-tile global loads
      const int j0n = j0 + 64;
      stk0 = *(const short8v*)&kb[(size_t)(j0n + srow0)*64 + sc*8];
      stk1 = *(const short8v*)&kb[(size_t)(j0n + srow1)*64 + sc*8];
      stv0 = *(const short8v*)&vtb[(size_t)srow0*2048 + j0n + sc*8];
      stv1 = *(const short8v*)&vtb[(size_t)srow1*2048 + j0n + sc*8];
    }

    // --- QK^T: 2 C-tiles (n=0,1), K=64 in 2 steps ---
    f32x4 c0 = {0,0,0,0}, c1 = {0,0,0,0};
    {
      const int jr0 = jh*32 + lrow, jr1 = jh*32 + 16 + lrow;
      const short8v b00 = *(const short8v*)&k_lds[jr0*64 + ((g*8) ^ swz)];
      const short8v b01 = *(const short8v*)&k_lds[jr0*64 + ((32 + g*8) ^ swz)];
      const short8v b10 = *(const short8v*)&k_lds[jr1*64 + ((g*8) ^ swz)];
      const short8v b11 = *(const short8v*)&k_lds[jr1*64 + ((32 + g*8) ^ swz)];
      c0 = MFMA16x16x32(aq0, b00, c0);
      c0 = MFMA16x16x32(aq1, b01, c0);
      c1 = MFMA16x16x32(aq0, b10, c1);
      c1 = MFMA16x16x32(aq1, b11, c1);
    }

    const float m0v = (1.0f - mb[j0 + jh*32 + lrow])      * -10000.0f;
    const float m1v = (1.0f - mb[j0 + jh*32 + 16 + lrow]) * -10000.0f;

    if (j0 <= i0 - 192) {            // whole tile -> bucket 0
      #pragma unroll
      for (int r = 0; r < 4; ++r) {
        const int il  = ih*16 + 4*g + r;
        const int wsw = ((4*g + r) & 7) << 3;
        const float p0 = __expf(c0[r]*0.125f + rs_lo[r] + m0v - 8.0f);
        const float p1 = __expf(c1[r]*0.125f + rs_lo[r] + m1v - 8.0f);
        qp_lds[il*64 + ((jh*32 + lrow) ^ wsw)]      = f2bf(p0);
        qp_lds[il*64 + ((jh*32 + 16 + lrow) ^ wsw)] = f2bf(p1);
        rpl_p[r] += p0 + p1; ls_p[r] += p0 + p1;
      }
    } else if (j0 >= i0 + 159) {     // whole tile -> bucket 255
      #pragma unroll
      for (int r = 0; r < 4; ++r) {
        const int il  = ih*16 + 4*g + r;
        const int wsw = ((4*g + r) & 7) << 3;
        const float p0 = __expf(c0[r]*0.125f + rs_hi[r] + m0v - 8.0f);
        const float p1 = __expf(c1[r]*0.125f + rs_hi[r] + m1v - 8.0f);
        qp_lds[il*64 + ((jh*32 + lrow) ^ wsw)]      = f2bf(p0);
        qp_lds[il*64 + ((jh*32 + 16 + lrow) ^ wsw)] = f2bf(p1);
        rph_p[r] += p0 + p1; ls_p[r] += p0 + p1;
      }
    } else {                         // band: read rs slot, overwrite with p
      #pragma unroll
      for (int r = 0; r < 4; ++r) {
        const int il  = ih*16 + 4*g + r;
        const int gi  = i0 + il;
        const int wsw = ((4*g + r) & 7) << 3;
        {
          const int jl = jh*32 + lrow, gj = j0 + jl;
          int rel = gj - gi; rel = rel < -128 ? -128 : (rel > 127 ? 127 : rel);
          const int bk = rel + 128;
          const int slot = il*256 + (((bk >> 3) ^ (il & 7)) << 3) + (bk & 7);
          const float p = __expf(c0[r]*0.125f + bf2f(rr_bf[slot]) + m0v - 8.0f);
          qp_lds[il*64 + (jl ^ wsw)] = f2bf(p);
          if (bk == 0)        rpl_p[r] += p;
          else if (bk == 255) rph_p[r] += p;
          else rr_bf[slot] = f2bf(p);
          ls_p[r] += p;
        }
        {
          const int jl = jh*32 + 16 + lrow, gj = j0 + jl;
          int rel = gj - gi; rel = rel < -128 ? -128 : (rel > 127 ? 127 : rel);
          const int bk = rel + 128;
          const int slot = il*256 + (((bk >> 3) ^ (il & 7)) << 3) + (bk & 7);
          const float p = __expf(c1[r]*0.125f + bf2f(rr_bf[slot]) + m1v - 8.0f);
          qp_lds[il*64 + (jl ^ wsw)] = f2bf(p);
          if (bk == 0)        rpl_p[r] += p;
          else if (bk == 255) rph_p[r] += p;
          else rr_bf[slot] = f2bf(p);
          ls_p[r] += p;
        }
      }
    }
    __syncthreads();                 // B1: p visible; all k(jt) reads done

    // k(jt+1) from regs -> LDS (k(jt) dead)
    if (have_next) {
      *(short8v*)&k_lds[srow0*64 + ((sc ^ (srow0 & 7))*8)] = stk0;
      *(short8v*)&k_lds[srow1*64 + ((sc ^ (srow1 & 7))*8)] = stk1;
    }

    // --- PV: ctx[i][d] += P[i][:] @ V[:, d] ---
    {
      const int prow = ih*16 + lrow;
      const short8v pa0 = *(const short8v*)&qp_lds[prow*64 + ((g*8) ^ swz)];
      const short8v pa1 = *(const short8v*)&qp_lds[prow*64 + ((32 + g*8) ^ swz)];
      const int d0 = jh*32 + lrow, d1 = jh*32 + 16 + lrow;
      const short8v vb00 = *(const short8v*)&vt_lds[d0*64 + ((g*8) ^ swz)];
      const short8v vb01 = *(const short8v*)&vt_lds[d0*64 + ((32 + g*8) ^ swz)];
      const short8v vb10 = *(const short8v*)&vt_lds[d1*64 + ((g*8) ^ swz)];
      const short8v vb11 = *(const short8v*)&vt_lds[d1*64 + ((32 + g*8) ^ swz)];
      ctx0 = MFMA16x16x32(pa0, vb00, ctx0);
      ctx0 = MFMA16x16x32(pa1, vb01, ctx0);
      ctx1 = MFMA16x16x32(pa0, vb10, ctx1);
      ctx1 = MFMA16x16x32(pa1, vb11, ctx1);
    }
    __syncthreads();                 // B2: PV reads done; k(jt+1) visible
  }

  // --- fold per-lane partials (edges + row sums), once ---
  #pragma unroll
  for (int r = 0; r < 4; ++r) {
    float a = ls_p[r], bl = rpl_p[r], bhv = rph_p[r];
    #pragma unroll
    for (int m = 1; m < 16; m <<= 1) {
      a   += __shfl_xor(a, m);
      bl  += __shfl_xor(bl, m);
      bhv += __shfl_xor(bhv, m);
    }
    if (lrow == 0) {
      const int il = ih*16 + 4*g + r;
      LDS_ATOMIC_ADD(&l_s[il], a);
      LDS_ATOMIC_ADD(&edge_f[2*il + 0], bl);
      LDS_ATOMIC_ADD(&edge_f[2*il + 1], bhv);
    }
  }
  __syncthreads();

  // zero stale-rs slots (j out of range) — only the 8/64 edge i-blocks
  if (i0 < 128) {
    for (int id = t; id < 4096; id += 256) {
      const int row = id >> 7, bk = (id & 127) + 1;       // bk 1..128
      if (bk <= 127 - (i0 + row))
        rr_bf[row*256 + (((bk >> 3) ^ (row & 7)) << 3) + (bk & 7)] = 0;
    }
  } else if (i0 >= 1920) {
    for (int id = t; id < 4096; id += 256) {
      const int row = id >> 7, bk = 254 - (id & 127);     // bk 127..254
      if (bk >= 2176 - (i0 + row))
        rr_bf[row*256 + (((bk >> 3) ^ (row & 7)) << 3) + (bk & 7)] = 0;
    }
  }
  // patch edge buckets
  if (t < 32) {
    const int row = t;
    rr_bf[row*256 + ((row & 7) << 3)]              = f2bf(edge_f[2*row + 0]);
    rr_bf[row*256 + (((31 ^ (row & 7)) << 3) + 7)] = f2bf(edge_f[2*row + 1]);
  }
  __syncthreads();

  // --- rel-value epilogue: ctx += rp @ rve (K=256) ---
  {
    const int arow = ih*16 + lrow;
    const int d0 = jh*32 + lrow, d1 = jh*32 + 16 + lrow;
    #pragma unroll
    for (int ks = 0; ks < 8; ++ks) {
      const short8v a  = *(const short8v*)&rr_bf[arow*256 + (((ks*4 + g) ^ (lrow & 7))*8)];
      const short8v b0 = *(const short8v*)&rvet[d0*256 + ks*32 + g*8];
      const short8v b1 = *(const short8v*)&rvet[d1*256 + ks*32 + g*8];
      ctx0 = MFMA16x16x32(a, b0, ctx0);
      ctx1 = MFMA16x16x32(a, b1, ctx1);
    }
  }

  // --- normalize + store ---
  #pragma unroll
  for (int r = 0; r < 4; ++r) {
    const int il = ih*16 + 4*g + r;
    const float invl = 1.0f / l_s[il];
    const int gi = i0 + il;
    out[(size_t)(b*2048 + gi)*768 + h*64 + jh*32 + lrow]      = ctx0[r] * invl;
    out[(size_t)(b*2048 + gi)*768 + h*64 + jh*32 + 16 + lrow] = ctx1[r] * invl;
  }
}

// ---------------- launcher ----------------
extern "C" void kernel_launch(void* const* d_in, const int* in_sizes, int n_in,
                              void* d_out, int out_size, void* d_ws, size_t ws_size,
                              hipStream_t stream) {
  const float* hs   = (const float*)d_in[0];
  const float* mask = (const float*)d_in[1];
  const float* Wq   = (const float*)d_in[2];
  const float* bq   = (const float*)d_in[3];
  const float* Wk   = (const float*)d_in[4];
  const float* bk   = (const float*)d_in[5];
  const float* Wv   = (const float*)d_in[6];
  const float* bv   = (const float*)d_in[7];
  const float* rke  = (const float*)d_in[8];
  const float* rve  = (const float*)d_in[9];
  // d_in[10] = indices, recomputed analytically on device.

  // Workspace (shorts, all disjoint): wt 1.77M | qbf/kbf/vbf/vtbf 3.1M ea |
  // rvet/rkeb 16K ea = 28.77 MB total.
  const size_t need_bytes = 28770304;
  if (ws_size < need_bytes) return;

  short* p     = (short*)d_ws;
  short* wtb   = p;                       // 1,769,472
  short* qbf   = p + 1769472;             // 3,145,728
  short* kbf   = p + 4915200;
  short* vbf   = p + 8060928;
  short* vtbf  = p + 11206656;
  short* rvet  = p + 14352384;            // 16,384
  short* rkeb  = p + 14368768;            // 16,384
  float* out   = (float*)d_out;

  prep_wt_kernel<<<dim3(12, 12, 3), dim3(256), 0, stream>>>(Wq, Wk, Wv, wtb);
  rvet_kernel<<<dim3(64), dim3(256), 0, stream>>>(rve, rke, rvet, rkeb);
  qkv_mfma_kernel<<<dim3(32, 6, 3), dim3(256), 0, stream>>>(
      hs, wtb, bq, bk, bv, qbf, kbf, vbf);
  transpose_v_kernel<<<dim3(32, 24), dim3(256), 0, stream>>>(vbf, vtbf);
  attn_mfma_kernel<<<dim3(64, 24), dim3(256), 0, stream>>>(
      qbf, kbf, vtbf, rkeb, rvet, mask, out);
}